// Round 8
// baseline (397.104 us; speedup 1.0000x reference)
//
#include <hip/hip_runtime.h>
#include <math.h>

#define N_NODES 50000
#define N_EDGES 100000
#define FNODE 22
#define HDIM 64
#define BN_EPS 1e-5f

typedef __attribute__((ext_vector_type(8))) short bfrag;   // 8 bf16 = A/B operand
typedef __attribute__((ext_vector_type(4))) float facc;    // 4 f32  = C/D
typedef __attribute__((ext_vector_type(4))) unsigned int uint4v;
typedef __attribute__((ext_vector_type(2))) unsigned int uint2v;

__device__ __forceinline__ float readlane_f(float v, int lane) {
    return __uint_as_float(__builtin_amdgcn_readlane(__float_as_uint(v), (unsigned)lane));
}
__device__ __forceinline__ unsigned f2bf(float x) {  // RNE f32->bf16
    unsigned u = __float_as_uint(x);
    return (u + 0x7FFFu + ((u >> 16) & 1u)) >> 16;
}
__device__ __forceinline__ unsigned pk2bf(float lo, float hi) {
    return f2bf(lo) | (f2bf(hi) << 16);
}

// h1[n][o] = b1[o] + sum_i x[n][i] * root1[i][o]   (8 nodes per wave, lane = o)
__global__ void k_node1(const float* __restrict__ x, const float* __restrict__ root1,
                        const float* __restrict__ b1, float* __restrict__ h1) {
    __shared__ float rt[FNODE * HDIM];
    for (int idx = threadIdx.x; idx < FNODE * HDIM; idx += blockDim.x) rt[idx] = root1[idx];
    __syncthreads();
    int lane = threadIdx.x & 63;
    int wpb = blockDim.x >> 6;
    int wid = blockIdx.x * wpb + (threadIdx.x >> 6);
    int nw = gridDim.x * wpb;
    const int ngroups = N_NODES / 8;
    float bload = b1[lane];
    for (int g = wid; g < ngroups; g += nw) {
        int nbase = g * 8;
        float xr[8], acc[8];
#pragma unroll
        for (int e = 0; e < 8; ++e) {
            xr[e] = (lane < FNODE) ? x[(nbase + e) * FNODE + lane] : 0.f;
            acc[e] = bload;
        }
#pragma unroll
        for (int i = 0; i < FNODE; ++i) {
            float r = rt[i * HDIM + lane];
#pragma unroll
            for (int e = 0; e < 8; ++e)
                acc[e] = fmaf(readlane_f(xr[e], i), r, acc[e]);
        }
#pragma unroll
        for (int e = 0; e < 8; ++e) h1[(nbase + e) * HDIM + lane] = acc[e];
    }
}

// MFMA edge kernel v4: LDS weights (fast path per R5/R7 ledger) with
//  - i-split across blocks (ICNT channels per block) -> small LDS -> 4 blocks/CU
//  - weight layout [q][i][e16] (uint4 = t-pair) + packed bias [i][e16] (uint2 = 4 bf16):
//    per i-channel only 2x ds_read_b128 + 1x ds_read_b64, conflict-free.
// A = edge attrs (16 edges/group, 2 groups), k0..3 = ea, k4 = 1.0; B = weights k0..3 + be k4.
// D layout [m89]: col(lane&15)=o, row((lane>>4)*4+reg)=edge -> contiguous-line atomics.
template <int INT, int ICNT, int HSTRIDE>
__launch_bounds__(256, 4)
__global__ void k_edge(const float* __restrict__ h, const float* __restrict__ ea,
                       const float* __restrict__ We, const float* __restrict__ be,
                       const int* __restrict__ eidx, float* __restrict__ out) {
    constexpr int ISPLIT = INT / ICNT;
    constexpr int INHT = INT * HDIM;          // full channel count (We row stride)
    __shared__ uint4v Wq[2 * ICNT * 16];      // [q][i][e16]: {w(t=2q) 8B, w(t=2q+1) 8B}
    __shared__ uint2v Bl[ICNT * 16];          // [i][e16]: {be(t0)|be(t1), be(t2)|be(t3)}
    __shared__ float hsl[4][32 * HSTRIDE];    // per-wave h rows (f32), channels [ibeg,+ICNT)

    int ibeg = (ISPLIT > 1) ? (blockIdx.x & (ISPLIT - 1)) * ICNT : 0;
    int tileblk = (ISPLIT > 1) ? (blockIdx.x >> 1) : blockIdx.x;

    for (int idx = threadIdx.x; idx < 2 * ICNT * 16; idx += blockDim.x) {
        int q = idx / (ICNT * 16);
        int rem = idx - q * (ICNT * 16);
        int i = rem >> 4, e = rem & 15;
        int c0 = (ibeg + i) * HDIM + (2 * q) * 16 + e;
        int c1 = c0 + 16;
        Wq[idx] = uint4v{pk2bf(We[c0], We[INHT + c0]),
                         pk2bf(We[2 * INHT + c0], We[3 * INHT + c0]),
                         pk2bf(We[c1], We[INHT + c1]),
                         pk2bf(We[2 * INHT + c1], We[3 * INHT + c1])};
    }
    for (int idx = threadIdx.x; idx < ICNT * 16; idx += blockDim.x) {
        int i = idx >> 4, e = idx & 15;
        int cb = (ibeg + i) * HDIM + e;
        Bl[idx] = uint2v{pk2bf(be[cb], be[cb + 16]), pk2bf(be[cb + 32], be[cb + 48])};
    }
    __syncthreads();

    int lane = threadIdx.x & 63;
    int e16 = lane & 15;                 // D column = o offset
    int orow4 = (lane >> 4) * 4;         // D row base = edge-within-group base
    int tile = tileblk * 4 + (threadIdx.x >> 6);
    int ebase = tile * 32;
    if (ebase >= N_EDGES) return;
    float* hs = &hsl[threadIdx.x >> 6][0];

    // A operands: lanes<16 carry k=0..4 = {ea[e], 1.0}; other k-slots zero
    bool act = lane < 16;
    float4 ea0 = ((const float4*)ea)[ebase + e16];
    float4 ea1 = ((const float4*)ea)[ebase + 16 + e16];
    unsigned aone = act ? 0x3F80u : 0u;
    bfrag A0 = __builtin_bit_cast(bfrag, uint4v{act ? pk2bf(ea0.x, ea0.y) : 0u,
                                                act ? pk2bf(ea0.z, ea0.w) : 0u, aone, 0u});
    bfrag A1 = __builtin_bit_cast(bfrag, uint4v{act ? pk2bf(ea1.x, ea1.y) : 0u,
                                                act ? pk2bf(ea1.z, ea1.w) : 0u, aone, 0u});

    // stage this wave's 32 h rows (channels [ibeg, ibeg+ICNT)) into its slab
    if constexpr (ICNT == 32) {
#pragma unroll
        for (int p = 0; p < 4; ++p) {
            int idx = p * 64 + lane;
            int r = idx >> 3, c4 = (idx & 7) << 2;
            int srcr = eidx[ebase + r];
            float4 v = *(const float4*)(h + (size_t)srcr * INT + ibeg + c4);
            *(float4*)&hs[r * HSTRIDE + c4] = v;
        }
    } else {
#pragma unroll
        for (int p = 0; p < (32 * ICNT) / 64; ++p) {   // 704/64 = 11 exact for ICNT=22
            int idx = p * 64 + lane;
            int r = idx / ICNT, c = idx - r * ICNT;
            int srcr = eidx[ebase + r];
            hs[r * HSTRIDE + c] = h[(size_t)srcr * INT + c];
        }
    }

    // dst row indices for this lane's 8 (group, reg) slots
    int dA[4], dB[4];
#pragma unroll
    for (int j = 0; j < 4; ++j) {
        dA[j] = eidx[N_EDGES + ebase + orow4 + j];
        dB[j] = eidx[N_EDGES + ebase + 16 + orow4 + j];
    }

    const facc zero4 = {0.f, 0.f, 0.f, 0.f};
    facc m0[4], m1[4];
#pragma unroll
    for (int t = 0; t < 4; ++t) { m0[t] = zero4; m1[t] = zero4; }

    constexpr int I4 = ICNT & ~3;
    for (int i0 = 0; i0 < I4; i0 += 4) {
        float4 ha[4], hb[4];
#pragma unroll
        for (int j = 0; j < 4; ++j) {
            ha[j] = *(const float4*)&hs[(orow4 + j) * HSTRIDE + i0];
            hb[j] = *(const float4*)&hs[(16 + orow4 + j) * HSTRIDE + i0];
        }
#pragma unroll
        for (int di = 0; di < 4; ++di) {
            int i = i0 + di;
            uint4v w01 = Wq[i * 16 + e16];                 // t0,t1 (ds_read_b128)
            uint4v w23 = Wq[ICNT * 16 + i * 16 + e16];     // t2,t3 (ds_read_b128)
            uint2v bw = Bl[i * 16 + e16];                  // 4 biases (ds_read_b64)
            uint4v bws = uint4v{bw.x & 0xFFFFu, bw.x >> 16, bw.y & 0xFFFFu, bw.y >> 16};
#pragma unroll
            for (int t = 0; t < 4; ++t) {
                unsigned wlo = (t == 0) ? w01.x : (t == 1) ? w01.z : (t == 2) ? w23.x : w23.z;
                unsigned whi = (t == 0) ? w01.y : (t == 1) ? w01.w : (t == 2) ? w23.y : w23.w;
                bfrag B = __builtin_bit_cast(bfrag, uint4v{wlo, whi, bws[t], 0u});
                facc t0 = __builtin_amdgcn_mfma_f32_16x16x32_bf16(A0, B, zero4, 0, 0, 0);
                facc t1 = __builtin_amdgcn_mfma_f32_16x16x32_bf16(A1, B, zero4, 0, 0, 0);
#pragma unroll
                for (int j = 0; j < 4; ++j) {
                    m0[t][j] = fmaf((&ha[j].x)[di], fmaxf(t0[j], 0.f), m0[t][j]);
                    m1[t][j] = fmaf((&hb[j].x)[di], fmaxf(t1[j], 0.f), m1[t][j]);
                }
            }
        }
    }
    if constexpr ((ICNT & 3) != 0) {       // ICNT=22 tail: i = I4, I4+1
        float2 ha[4], hb[4];
#pragma unroll
        for (int j = 0; j < 4; ++j) {
            ha[j] = *(const float2*)&hs[(orow4 + j) * HSTRIDE + I4];
            hb[j] = *(const float2*)&hs[(16 + orow4 + j) * HSTRIDE + I4];
        }
#pragma unroll
        for (int di = 0; di < 2; ++di) {
            int i = I4 + di;
            uint4v w01 = Wq[i * 16 + e16];
            uint4v w23 = Wq[ICNT * 16 + i * 16 + e16];
            uint2v bw = Bl[i * 16 + e16];
            uint4v bws = uint4v{bw.x & 0xFFFFu, bw.x >> 16, bw.y & 0xFFFFu, bw.y >> 16};
#pragma unroll
            for (int t = 0; t < 4; ++t) {
                unsigned wlo = (t == 0) ? w01.x : (t == 1) ? w01.z : (t == 2) ? w23.x : w23.z;
                unsigned whi = (t == 0) ? w01.y : (t == 1) ? w01.w : (t == 2) ? w23.y : w23.w;
                bfrag B = __builtin_bit_cast(bfrag, uint4v{wlo, whi, bws[t], 0u});
                facc t0 = __builtin_amdgcn_mfma_f32_16x16x32_bf16(A0, B, zero4, 0, 0, 0);
                facc t1 = __builtin_amdgcn_mfma_f32_16x16x32_bf16(A1, B, zero4, 0, 0, 0);
#pragma unroll
                for (int j = 0; j < 4; ++j) {
                    m0[t][j] = fmaf((&ha[j].x)[di], fmaxf(t0[j], 0.f), m0[t][j]);
                    m1[t][j] = fmaf((&hb[j].x)[di], fmaxf(t1[j], 0.f), m1[t][j]);
                }
            }
        }
    }

    // epilogue: each atomic instr = 4 edges x 16 contiguous dwords (fully-covered lines)
#pragma unroll
    for (int t = 0; t < 4; ++t) {
#pragma unroll
        for (int j = 0; j < 4; ++j) {
            atomicAdd(&out[(size_t)dA[j] * HDIM + t * 16 + e16], m0[t][j]);
            atomicAdd(&out[(size_t)dB[j] * HDIM + t * 16 + e16], m1[t][j]);
        }
    }
}

// Per-channel sum & sumsq over N rows -> stats[0:64]=sum, stats[64:128]=sumsq (pre-zeroed)
__global__ void k_stats(const float* __restrict__ hbuf, float* stats) {
    int c = threadIdx.x & 63;
    int r = threadIdx.x >> 6;
    int rowsPer = blockDim.x >> 6;
    float s = 0.f, q = 0.f;
    for (int n = blockIdx.x * rowsPer + r; n < N_NODES; n += gridDim.x * rowsPer) {
        float v = hbuf[n * HDIM + c];
        s += v;
        q = fmaf(v, v, q);
    }
    __shared__ float ls[4][64], lq[4][64];
    ls[r][c] = s;
    lq[r][c] = q;
    __syncthreads();
    if (r == 0) {
        s = ls[0][c] + ls[1][c] + ls[2][c] + ls[3][c];
        q = lq[0][c] + lq[1][c] + lq[2][c] + lq[3][c];
        atomicAdd(&stats[c], s);
        atomicAdd(&stats[64 + c], q);
    }
}

__global__ void k_finalize(const float* stats_in, const float* __restrict__ g,
                           const float* __restrict__ beta, float* as_out) {
    int c = threadIdx.x;
    float mu = stats_in[c] * (1.f / N_NODES);
    float var = stats_in[64 + c] * (1.f / N_NODES) - mu * mu;
    var = fmaxf(var, 0.f);
    float a = g[c] * rsqrtf(var + BN_EPS);
    as_out[c] = a;
    as_out[64 + c] = beta[c] - mu * a;
}

// h1n = relu(BN1(h1)); h2 = b2 + h1n @ root2  (8 nodes per wave; h2 aliases h1 safely)
__global__ void k_apply1(const float* h1, const float* __restrict__ as1,
                         const float* __restrict__ root2, const float* __restrict__ b2,
                         float* __restrict__ h1n, float* h2) {
    __shared__ float rt[HDIM * HDIM];
    for (int idx = threadIdx.x; idx < HDIM * HDIM; idx += blockDim.x) rt[idx] = root2[idx];
    __syncthreads();
    int lane = threadIdx.x & 63;
    int wpb = blockDim.x >> 6;
    int wid = blockIdx.x * wpb + (threadIdx.x >> 6);
    int nw = gridDim.x * wpb;
    const int ngroups = N_NODES / 8;
    float a = as1[lane], s = as1[64 + lane];
    float bload = b2[lane];
    for (int g = wid; g < ngroups; g += nw) {
        int nbase = g * 8;
        float v[8], acc[8];
#pragma unroll
        for (int e = 0; e < 8; ++e) {
            v[e] = fmaxf(fmaf(h1[(nbase + e) * HDIM + lane], a, s), 0.f);
            h1n[(nbase + e) * HDIM + lane] = v[e];
            acc[e] = bload;
        }
#pragma unroll 4
        for (int i = 0; i < HDIM; ++i) {
            float r = rt[i * HDIM + lane];
#pragma unroll
            for (int e = 0; e < 8; ++e)
                acc[e] = fmaf(readlane_f(v[e], i), r, acc[e]);
        }
#pragma unroll
        for (int e = 0; e < 8; ++e) h2[(nbase + e) * HDIM + lane] = acc[e];
    }
}

// out[n] = sigmoid( sum_c relu(BN2(h2[n][c])) * Wfc[c] + bfc )
__global__ void k_final(const float* __restrict__ h2, const float* __restrict__ as2,
                        const float* __restrict__ Wfc, const float* __restrict__ bfc,
                        float* __restrict__ out) {
    int lane = threadIdx.x & 63;
    int n = blockIdx.x * (blockDim.x >> 6) + (threadIdx.x >> 6);
    if (n >= N_NODES) return;
    float a = as2[lane], s = as2[64 + lane];
    float v = fmaxf(fmaf(h2[n * HDIM + lane], a, s), 0.f) * Wfc[lane];
#pragma unroll
    for (int off = 32; off > 0; off >>= 1) v += __shfl_xor(v, off, 64);
    if (lane == 0) out[n] = 1.f / (1.f + expf(-(v + bfc[0])));
}

extern "C" void kernel_launch(void* const* d_in, const int* in_sizes, int n_in,
                              void* d_out, int out_size, void* d_ws, size_t ws_size,
                              hipStream_t stream) {
    const float* x     = (const float*)d_in[0];
    const float* ea    = (const float*)d_in[1];
    const float* We1   = (const float*)d_in[2];
    const float* be1   = (const float*)d_in[3];
    const float* root1 = (const float*)d_in[4];
    const float* b1    = (const float*)d_in[5];
    const float* g1    = (const float*)d_in[6];
    const float* beta1 = (const float*)d_in[7];
    const float* We2   = (const float*)d_in[8];
    const float* be2   = (const float*)d_in[9];
    const float* root2 = (const float*)d_in[10];
    const float* b2    = (const float*)d_in[11];
    const float* g2    = (const float*)d_in[12];
    const float* beta2 = (const float*)d_in[13];
    const float* Wfc   = (const float*)d_in[14];
    const float* bfc   = (const float*)d_in[15];
    const int*   eidx  = (const int*)d_in[16];
    float* out = (float*)d_out;

    char* ws = (char*)d_ws;
    const size_t nbuf = (size_t)N_NODES * HDIM * sizeof(float);
    float* h1    = (float*)ws;            // [N,64]
    float* h1n   = (float*)(ws + nbuf);   // [N,64]
    float* h2    = h1;                    // alias: h1 dead after k_apply1 reads it
    float* stats = (float*)(ws + 2 * nbuf);

    hipMemsetAsync(stats, 0, 512 * sizeof(float), stream);

    const int edgeBlocks1 = (N_EDGES / 32 + 3) / 4;      // 782, ISPLIT=1
    const int edgeBlocks2 = 2 * edgeBlocks1;             // 1564, ISPLIT=2 (i-halves)
    const int nodeBlocks = (N_NODES + 3) / 4;

    k_node1<<<512, 256, 0, stream>>>(x, root1, b1, h1);
    k_edge<FNODE, FNODE, 24><<<edgeBlocks1, 256, 0, stream>>>(x, ea, We1, be1, eidx, h1);
    k_stats<<<256, 256, 0, stream>>>(h1, stats);
    k_finalize<<<1, 64, 0, stream>>>(stats, g1, beta1, stats + 128);
    k_apply1<<<1024, 256, 0, stream>>>(h1, stats + 128, root2, b2, h1n, h2);
    k_edge<HDIM, 32, 36><<<edgeBlocks2, 256, 0, stream>>>(h1n, ea, We2, be2, eidx, h2);
    k_stats<<<256, 256, 0, stream>>>(h2, stats + 256);
    k_finalize<<<1, 64, 0, stream>>>(stats + 256, g2, beta2, stats + 384);
    k_final<<<nodeBlocks, 256, 0, stream>>>(h2, stats + 384, Wfc, bfc, out);
}

// Round 9
// 214.170 us; speedup vs baseline: 1.8542x; 1.8542x over previous
//
#include <hip/hip_runtime.h>
#include <math.h>

#define N_NODES 50000
#define N_EDGES 100000
#define FNODE 22
#define HDIM 64
#define BN_EPS 1e-5f

typedef __attribute__((ext_vector_type(8))) short bfrag;   // 8 bf16 = A/B operand
typedef __attribute__((ext_vector_type(4))) float facc;    // 4 f32  = C/D
typedef __attribute__((ext_vector_type(4))) unsigned int uint4v;
typedef __attribute__((ext_vector_type(2))) unsigned int uint2v;

__device__ __forceinline__ float readlane_f(float v, int lane) {
    return __uint_as_float(__builtin_amdgcn_readlane(__float_as_uint(v), (unsigned)lane));
}
__device__ __forceinline__ unsigned f2bf(float x) {  // RNE f32->bf16
    unsigned u = __float_as_uint(x);
    return (u + 0x7FFFu + ((u >> 16) & 1u)) >> 16;
}
__device__ __forceinline__ unsigned pk2bf(float lo, float hi) {
    return f2bf(lo) | (f2bf(hi) << 16);
}

// h1[n][o] = b1[o] + sum_i x[n][i] * root1[i][o]   (8 nodes per wave, lane = o)
__global__ void k_node1(const float* __restrict__ x, const float* __restrict__ root1,
                        const float* __restrict__ b1, float* __restrict__ h1) {
    __shared__ float rt[FNODE * HDIM];
    for (int idx = threadIdx.x; idx < FNODE * HDIM; idx += blockDim.x) rt[idx] = root1[idx];
    __syncthreads();
    int lane = threadIdx.x & 63;
    int wpb = blockDim.x >> 6;
    int wid = blockIdx.x * wpb + (threadIdx.x >> 6);
    int nw = gridDim.x * wpb;
    const int ngroups = N_NODES / 8;
    float bload = b1[lane];
    for (int g = wid; g < ngroups; g += nw) {
        int nbase = g * 8;
        float xr[8], acc[8];
#pragma unroll
        for (int e = 0; e < 8; ++e) {
            xr[e] = (lane < FNODE) ? x[(nbase + e) * FNODE + lane] : 0.f;
            acc[e] = bload;
        }
#pragma unroll
        for (int i = 0; i < FNODE; ++i) {
            float r = rt[i * HDIM + lane];
#pragma unroll
            for (int e = 0; e < 8; ++e)
                acc[e] = fmaf(readlane_f(xr[e], i), r, acc[e]);
        }
#pragma unroll
        for (int e = 0; e < 8; ++e) h1[(nbase + e) * HDIM + lane] = acc[e];
    }
}

// MFMA edge kernel v5: o-split across block pairs (obeg = 0 or 32).
//  - Line-disjoint atomics: o-half blocks write different 64B lines of each row (R8 lesson).
//  - LDS holds only the o-half weight tile (16KB) + transposed bias (R7 lesson: weights
//    must be LDS); NO h-slab -> ~20.7KB LDS -> 4 blocks/CU (2x R5 occupancy).
//  - h values read directly from global (16-lane broadcast; L1/L2-served).
// A = edge attrs (16 edges/group, 2 groups), k0..3 = ea, k4 = 1.0; B = weights k0..3 + be k4.
// D layout [m89]: col(lane&15)=o, row((lane>>4)*4+reg)=edge -> contiguous-line atomics.
template <int IN, int BSTRIDE, int CHUNK>
__launch_bounds__(256, 4)
__global__ void k_edge(const float* __restrict__ h, const float* __restrict__ ea,
                       const float* __restrict__ We, const float* __restrict__ be,
                       const int* __restrict__ eidx, float* __restrict__ out) {
    constexpr int INH = IN * HDIM;
    __shared__ unsigned Wlds[IN * 32 * 2];        // [(i*32+oloc)*2 + w01/w23]
    __shared__ unsigned short Bel[32 * BSTRIDE];  // transposed bias [oloc*BSTRIDE + i]

    int obeg = (blockIdx.x & 1) * 32;
    int tileblk = blockIdx.x >> 1;

    for (int idx = threadIdx.x; idx < IN * 32; idx += 256) {
        int i = idx >> 5, oloc = idx & 31;
        int c = i * HDIM + obeg + oloc;
        Wlds[2 * idx]     = pk2bf(We[c], We[INH + c]);
        Wlds[2 * idx + 1] = pk2bf(We[2 * INH + c], We[3 * INH + c]);
    }
    for (int idx = threadIdx.x; idx < 32 * IN; idx += 256) {
        int oloc = idx / IN, i = idx - oloc * IN;
        Bel[oloc * BSTRIDE + i] = (unsigned short)f2bf(be[i * HDIM + obeg + oloc]);
    }
    __syncthreads();

    int lane = threadIdx.x & 63;
    int e16 = lane & 15;                 // D column = o offset within the 16-tile
    int orow4 = (lane >> 4) * 4;         // D row base = edge-within-group base
    int tile = tileblk * 4 + (threadIdx.x >> 6);
    int ebase = tile * 32;
    if (ebase >= N_EDGES) return;

    // A operands: lanes<16 carry k=0..4 = {ea[e], 1.0}; other k-slots zero
    bool act = lane < 16;
    float4 ea0 = ((const float4*)ea)[ebase + e16];
    float4 ea1 = ((const float4*)ea)[ebase + 16 + e16];
    unsigned aone = act ? 0x3F80u : 0u;
    bfrag A0 = __builtin_bit_cast(bfrag, uint4v{act ? pk2bf(ea0.x, ea0.y) : 0u,
                                                act ? pk2bf(ea0.z, ea0.w) : 0u, aone, 0u});
    bfrag A1 = __builtin_bit_cast(bfrag, uint4v{act ? pk2bf(ea1.x, ea1.y) : 0u,
                                                act ? pk2bf(ea1.z, ea1.w) : 0u, aone, 0u});

    // src row pointers + dst rows for this lane's 8 (group, reg) slots
    const float* pA[4];
    const float* pB[4];
    int dA[4], dB[4];
#pragma unroll
    for (int j = 0; j < 4; ++j) {
        pA[j] = h + (size_t)eidx[ebase + orow4 + j] * IN;
        pB[j] = h + (size_t)eidx[ebase + 16 + orow4 + j] * IN;
        dA[j] = eidx[N_EDGES + ebase + orow4 + j];
        dB[j] = eidx[N_EDGES + ebase + 16 + orow4 + j];
    }

    const facc zero4 = {0.f, 0.f, 0.f, 0.f};
    facc m0[2] = {zero4, zero4}, m1[2] = {zero4, zero4};

    for (int i0 = 0; i0 < IN; i0 += CHUNK) {
        float hA[4][CHUNK], hB[4][CHUNK];
        if constexpr (CHUNK == 4) {
#pragma unroll
            for (int j = 0; j < 4; ++j) {
                float4 v = *(const float4*)(pA[j] + i0);   // rows 256B-aligned (IN=64)
                hA[j][0] = v.x; hA[j][1] = v.y; hA[j][2] = v.z; hA[j][3] = v.w;
                float4 u = *(const float4*)(pB[j] + i0);
                hB[j][0] = u.x; hB[j][1] = u.y; hB[j][2] = u.z; hB[j][3] = u.w;
            }
        } else {
#pragma unroll
            for (int j = 0; j < 4; ++j) {
                float2 v = *(const float2*)(pA[j] + i0);   // rows 8B-aligned (IN=22)
                hA[j][0] = v.x; hA[j][1] = v.y;
                float2 u = *(const float2*)(pB[j] + i0);
                hB[j][0] = u.x; hB[j][1] = u.y;
            }
        }
#pragma unroll
        for (int t = 0; t < 2; ++t) {
            unsigned bws[CHUNK];
            if constexpr (CHUNK == 4) {
                uint2v bq = *(const uint2v*)&Bel[(t * 16 + e16) * BSTRIDE + i0];
                bws[0] = bq.x & 0xFFFFu; bws[1] = bq.x >> 16;
                bws[2] = bq.y & 0xFFFFu; bws[3] = bq.y >> 16;
            } else {
                unsigned bq = *(const unsigned*)&Bel[(t * 16 + e16) * BSTRIDE + i0];
                bws[0] = bq & 0xFFFFu; bws[1] = bq >> 16;
            }
#pragma unroll
            for (int di = 0; di < CHUNK; ++di) {
                uint2v wv = *(const uint2v*)&Wlds[2 * ((i0 + di) * 32 + t * 16 + e16)];
                bfrag B = __builtin_bit_cast(bfrag, uint4v{wv.x, wv.y, bws[di], 0u});
                facc t0 = __builtin_amdgcn_mfma_f32_16x16x32_bf16(A0, B, zero4, 0, 0, 0);
                facc t1 = __builtin_amdgcn_mfma_f32_16x16x32_bf16(A1, B, zero4, 0, 0, 0);
#pragma unroll
                for (int j = 0; j < 4; ++j) {
                    m0[t][j] = fmaf(hA[j][di], fmaxf(t0[j], 0.f), m0[t][j]);
                    m1[t][j] = fmaf(hB[j][di], fmaxf(t1[j], 0.f), m1[t][j]);
                }
            }
        }
    }

    // epilogue: each atomic instr = 4 edges x 16 contiguous dwords (fully-covered lines,
    // o-half-disjoint across the block pair)
#pragma unroll
    for (int t = 0; t < 2; ++t) {
#pragma unroll
        for (int j = 0; j < 4; ++j) {
            atomicAdd(&out[(size_t)dA[j] * HDIM + obeg + t * 16 + e16], m0[t][j]);
            atomicAdd(&out[(size_t)dB[j] * HDIM + obeg + t * 16 + e16], m1[t][j]);
        }
    }
}

// Per-channel sum & sumsq over N rows -> stats[0:64]=sum, stats[64:128]=sumsq (pre-zeroed)
__global__ void k_stats(const float* __restrict__ hbuf, float* stats) {
    int c = threadIdx.x & 63;
    int r = threadIdx.x >> 6;
    int rowsPer = blockDim.x >> 6;
    float s = 0.f, q = 0.f;
    for (int n = blockIdx.x * rowsPer + r; n < N_NODES; n += gridDim.x * rowsPer) {
        float v = hbuf[n * HDIM + c];
        s += v;
        q = fmaf(v, v, q);
    }
    __shared__ float ls[4][64], lq[4][64];
    ls[r][c] = s;
    lq[r][c] = q;
    __syncthreads();
    if (r == 0) {
        s = ls[0][c] + ls[1][c] + ls[2][c] + ls[3][c];
        q = lq[0][c] + lq[1][c] + lq[2][c] + lq[3][c];
        atomicAdd(&stats[c], s);
        atomicAdd(&stats[64 + c], q);
    }
}

__global__ void k_finalize(const float* stats_in, const float* __restrict__ g,
                           const float* __restrict__ beta, float* as_out) {
    int c = threadIdx.x;
    float mu = stats_in[c] * (1.f / N_NODES);
    float var = stats_in[64 + c] * (1.f / N_NODES) - mu * mu;
    var = fmaxf(var, 0.f);
    float a = g[c] * rsqrtf(var + BN_EPS);
    as_out[c] = a;
    as_out[64 + c] = beta[c] - mu * a;
}

// h1n = relu(BN1(h1)); h2 = b2 + h1n @ root2  (8 nodes per wave; h2 aliases h1 safely)
__global__ void k_apply1(const float* h1, const float* __restrict__ as1,
                         const float* __restrict__ root2, const float* __restrict__ b2,
                         float* __restrict__ h1n, float* h2) {
    __shared__ float rt[HDIM * HDIM];
    for (int idx = threadIdx.x; idx < HDIM * HDIM; idx += blockDim.x) rt[idx] = root2[idx];
    __syncthreads();
    int lane = threadIdx.x & 63;
    int wpb = blockDim.x >> 6;
    int wid = blockIdx.x * wpb + (threadIdx.x >> 6);
    int nw = gridDim.x * wpb;
    const int ngroups = N_NODES / 8;
    float a = as1[lane], s = as1[64 + lane];
    float bload = b2[lane];
    for (int g = wid; g < ngroups; g += nw) {
        int nbase = g * 8;
        float v[8], acc[8];
#pragma unroll
        for (int e = 0; e < 8; ++e) {
            v[e] = fmaxf(fmaf(h1[(nbase + e) * HDIM + lane], a, s), 0.f);
            h1n[(nbase + e) * HDIM + lane] = v[e];
            acc[e] = bload;
        }
#pragma unroll 4
        for (int i = 0; i < HDIM; ++i) {
            float r = rt[i * HDIM + lane];
#pragma unroll
            for (int e = 0; e < 8; ++e)
                acc[e] = fmaf(readlane_f(v[e], i), r, acc[e]);
        }
#pragma unroll
        for (int e = 0; e < 8; ++e) h2[(nbase + e) * HDIM + lane] = acc[e];
    }
}

// out[n] = sigmoid( sum_c relu(BN2(h2[n][c])) * Wfc[c] + bfc )
__global__ void k_final(const float* __restrict__ h2, const float* __restrict__ as2,
                        const float* __restrict__ Wfc, const float* __restrict__ bfc,
                        float* __restrict__ out) {
    int lane = threadIdx.x & 63;
    int n = blockIdx.x * (blockDim.x >> 6) + (threadIdx.x >> 6);
    if (n >= N_NODES) return;
    float a = as2[lane], s = as2[64 + lane];
    float v = fmaxf(fmaf(h2[n * HDIM + lane], a, s), 0.f) * Wfc[lane];
#pragma unroll
    for (int off = 32; off > 0; off >>= 1) v += __shfl_xor(v, off, 64);
    if (lane == 0) out[n] = 1.f / (1.f + expf(-(v + bfc[0])));
}

extern "C" void kernel_launch(void* const* d_in, const int* in_sizes, int n_in,
                              void* d_out, int out_size, void* d_ws, size_t ws_size,
                              hipStream_t stream) {
    const float* x     = (const float*)d_in[0];
    const float* ea    = (const float*)d_in[1];
    const float* We1   = (const float*)d_in[2];
    const float* be1   = (const float*)d_in[3];
    const float* root1 = (const float*)d_in[4];
    const float* b1    = (const float*)d_in[5];
    const float* g1    = (const float*)d_in[6];
    const float* beta1 = (const float*)d_in[7];
    const float* We2   = (const float*)d_in[8];
    const float* be2   = (const float*)d_in[9];
    const float* root2 = (const float*)d_in[10];
    const float* b2    = (const float*)d_in[11];
    const float* g2    = (const float*)d_in[12];
    const float* beta2 = (const float*)d_in[13];
    const float* Wfc   = (const float*)d_in[14];
    const float* bfc   = (const float*)d_in[15];
    const int*   eidx  = (const int*)d_in[16];
    float* out = (float*)d_out;

    char* ws = (char*)d_ws;
    const size_t nbuf = (size_t)N_NODES * HDIM * sizeof(float);
    float* h1    = (float*)ws;            // [N,64]
    float* h1n   = (float*)(ws + nbuf);   // [N,64]
    float* h2    = h1;                    // alias: h1 dead after k_apply1 reads it
    float* stats = (float*)(ws + 2 * nbuf);

    hipMemsetAsync(stats, 0, 512 * sizeof(float), stream);

    const int edgeBlocks = 2 * ((N_EDGES / 32 + 3) / 4);  // 1564: o-half pairs
    const int nodeBlocks = (N_NODES + 3) / 4;

    k_node1<<<512, 256, 0, stream>>>(x, root1, b1, h1);
    k_edge<FNODE, 24, 2><<<edgeBlocks, 256, 0, stream>>>(x, ea, We1, be1, eidx, h1);
    k_stats<<<256, 256, 0, stream>>>(h1, stats);
    k_finalize<<<1, 64, 0, stream>>>(stats, g1, beta1, stats + 128);
    k_apply1<<<1024, 256, 0, stream>>>(h1, stats + 128, root2, b2, h1n, h2);
    k_edge<HDIM, 68, 4><<<edgeBlocks, 256, 0, stream>>>(h1n, ea, We2, be2, eidx, h2);
    k_stats<<<256, 256, 0, stream>>>(h2, stats + 256);
    k_finalize<<<1, 64, 0, stream>>>(stats + 256, g2, beta2, stats + 384);
    k_final<<<nodeBlocks, 256, 0, stream>>>(h2, stats + 384, Wfc, bfc, out);
}

// Round 10
// 184.798 us; speedup vs baseline: 2.1488x; 1.1589x over previous
//
#include <hip/hip_runtime.h>
#include <math.h>

#define N_NODES 50000
#define N_EDGES 100000
#define FNODE 22
#define HDIM 64
#define BN_EPS 1e-5f

typedef __attribute__((ext_vector_type(8))) short bfrag;   // 8 bf16 = A/B operand
typedef __attribute__((ext_vector_type(4))) float facc;    // 4 f32  = C/D
typedef __attribute__((ext_vector_type(4))) unsigned int uint4v;

__device__ __forceinline__ float readlane_f(float v, int lane) {
    return __uint_as_float(__builtin_amdgcn_readlane(__float_as_uint(v), (unsigned)lane));
}
__device__ __forceinline__ unsigned f2bf(float x) {  // RNE f32->bf16
    unsigned u = __float_as_uint(x);
    return (u + 0x7FFFu + ((u >> 16) & 1u)) >> 16;
}
__device__ __forceinline__ unsigned pk2bf(float lo, float hi) {
    return f2bf(lo) | (f2bf(hi) << 16);
}

// h1[n][o] = b1[o] + sum_i x[n][i] * root1[i][o]   (8 nodes per wave, lane = o)
__global__ void k_node1(const float* __restrict__ x, const float* __restrict__ root1,
                        const float* __restrict__ b1, float* __restrict__ h1) {
    __shared__ float rt[FNODE * HDIM];
    for (int idx = threadIdx.x; idx < FNODE * HDIM; idx += blockDim.x) rt[idx] = root1[idx];
    __syncthreads();
    int lane = threadIdx.x & 63;
    int wpb = blockDim.x >> 6;
    int wid = blockIdx.x * wpb + (threadIdx.x >> 6);
    int nw = gridDim.x * wpb;
    const int ngroups = N_NODES / 8;
    float bload = b1[lane];
    for (int g = wid; g < ngroups; g += nw) {
        int nbase = g * 8;
        float xr[8], acc[8];
#pragma unroll
        for (int e = 0; e < 8; ++e) {
            xr[e] = (lane < FNODE) ? x[(nbase + e) * FNODE + lane] : 0.f;
            acc[e] = bload;
        }
#pragma unroll
        for (int i = 0; i < FNODE; ++i) {
            float r = rt[i * HDIM + lane];
#pragma unroll
            for (int e = 0; e < 8; ++e)
                acc[e] = fmaf(readlane_f(xr[e], i), r, acc[e]);
        }
#pragma unroll
        for (int e = 0; e < 8; ++e) h1[(nbase + e) * HDIM + lane] = acc[e];
    }
}

// MFMA edge kernel v6: o-split block pairs (obeg 0/32), LDS holds PRE-ASSEMBLED
// B-fragments {w01,w23,be,0} (uint4 per (i,oloc)) -> inner iter = 1 ds_read_b128 +
// 2 MFMA + 8 fmax + 8 fma. No operand-assembly movs, no bias table.
// A = edge attrs (16 edges/group, 2 groups), k0..3 = ea, k4 = 1.0.
// D layout [m89]: col(lane&15)=o, row((lane>>4)*4+reg)=edge -> contiguous-line atomics,
// o-halves line-disjoint (R8 lesson).
template <int IN, int CHUNK>
__launch_bounds__(256, 4)
__global__ void k_edge(const float* __restrict__ h, const float* __restrict__ ea,
                       const float* __restrict__ We, const float* __restrict__ be,
                       const int* __restrict__ eidx, float* __restrict__ out) {
    constexpr int INH = IN * HDIM;
    __shared__ uint4v Wf[IN * 32];   // [i*32 + oloc] = B-fragment words

    int obeg = (blockIdx.x & 1) * 32;
    int tileblk = blockIdx.x >> 1;

    for (int idx = threadIdx.x; idx < IN * 32; idx += 256) {
        int i = idx >> 5, oloc = idx & 31;
        int c = i * HDIM + obeg + oloc;
        Wf[idx] = uint4v{pk2bf(We[c], We[INH + c]),
                         pk2bf(We[2 * INH + c], We[3 * INH + c]),
                         f2bf(be[c]), 0u};
    }
    __syncthreads();

    int lane = threadIdx.x & 63;
    int e16 = lane & 15;                 // D column = o offset within 16-tile
    int orow4 = (lane >> 4) * 4;         // D row base = edge-within-group base
    int tile = tileblk * 4 + (threadIdx.x >> 6);
    int ebase = tile * 32;
    if (ebase >= N_EDGES) return;

    // A operands: lanes<16 carry k=0..4 = {ea[e], 1.0}; other k-slots zero
    bool act = lane < 16;
    float4 ea0 = ((const float4*)ea)[ebase + e16];
    float4 ea1 = ((const float4*)ea)[ebase + 16 + e16];
    unsigned aone = act ? 0x3F80u : 0u;
    bfrag A0 = __builtin_bit_cast(bfrag, uint4v{act ? pk2bf(ea0.x, ea0.y) : 0u,
                                                act ? pk2bf(ea0.z, ea0.w) : 0u, aone, 0u});
    bfrag A1 = __builtin_bit_cast(bfrag, uint4v{act ? pk2bf(ea1.x, ea1.y) : 0u,
                                                act ? pk2bf(ea1.z, ea1.w) : 0u, aone, 0u});

    // src row pointers + dst rows for this lane's 8 (group, reg) slots
    const float* pA[4];
    const float* pB[4];
    int dA[4], dB[4];
#pragma unroll
    for (int j = 0; j < 4; ++j) {
        pA[j] = h + (size_t)eidx[ebase + orow4 + j] * IN;
        pB[j] = h + (size_t)eidx[ebase + 16 + orow4 + j] * IN;
        dA[j] = eidx[N_EDGES + ebase + orow4 + j];
        dB[j] = eidx[N_EDGES + ebase + 16 + orow4 + j];
    }

    const facc zero4 = {0.f, 0.f, 0.f, 0.f};
    facc m0[2] = {zero4, zero4}, m1[2] = {zero4, zero4};

    for (int i0 = 0; i0 < IN; i0 += CHUNK) {
        float hA[4][CHUNK], hB[4][CHUNK];
        if constexpr (CHUNK == 4) {
#pragma unroll
            for (int j = 0; j < 4; ++j) {
                float4 v = *(const float4*)(pA[j] + i0);   // rows 256B-aligned (IN=64)
                hA[j][0] = v.x; hA[j][1] = v.y; hA[j][2] = v.z; hA[j][3] = v.w;
                float4 u = *(const float4*)(pB[j] + i0);
                hB[j][0] = u.x; hB[j][1] = u.y; hB[j][2] = u.z; hB[j][3] = u.w;
            }
        } else {
#pragma unroll
            for (int j = 0; j < 4; ++j) {
                float2 v = *(const float2*)(pA[j] + i0);   // rows 8B-aligned (IN=22)
                hA[j][0] = v.x; hA[j][1] = v.y;
                float2 u = *(const float2*)(pB[j] + i0);
                hB[j][0] = u.x; hB[j][1] = u.y;
            }
        }
#pragma unroll
        for (int t = 0; t < 2; ++t) {
#pragma unroll
            for (int di = 0; di < CHUNK; ++di) {
                bfrag B = __builtin_bit_cast(bfrag, Wf[(i0 + di) * 32 + t * 16 + e16]);
                facc t0 = __builtin_amdgcn_mfma_f32_16x16x32_bf16(A0, B, zero4, 0, 0, 0);
                facc t1 = __builtin_amdgcn_mfma_f32_16x16x32_bf16(A1, B, zero4, 0, 0, 0);
#pragma unroll
                for (int j = 0; j < 4; ++j) {
                    m0[t][j] = fmaf(hA[j][di], fmaxf(t0[j], 0.f), m0[t][j]);
                    m1[t][j] = fmaf(hB[j][di], fmaxf(t1[j], 0.f), m1[t][j]);
                }
            }
        }
    }

    // epilogue: each atomic instr = 4 edges x 16 contiguous dwords (fully-covered lines)
#pragma unroll
    for (int t = 0; t < 2; ++t) {
#pragma unroll
        for (int j = 0; j < 4; ++j) {
            atomicAdd(&out[(size_t)dA[j] * HDIM + obeg + t * 16 + e16], m0[t][j]);
            atomicAdd(&out[(size_t)dB[j] * HDIM + obeg + t * 16 + e16], m1[t][j]);
        }
    }
}

// Pack root2 into MFMA B-fragments: Bt[(ot*2+q)*64 + lane] covers o-tile ot, k-chunk q.
// B[k=i][n=o]: lane holds i = q*32 + (lane>>4)*8 + r (r=0..7), o = ot*16 + (lane&15).
__global__ void k_packB(const float* __restrict__ root2, uint4v* __restrict__ Bt) {
    int t = threadIdx.x;           // 256 threads: ot = t>>6, lane = t&63
    int ot = t >> 6, lane = t & 63;
    int o = ot * 16 + (lane & 15);
    int kg = lane >> 4;
#pragma unroll
    for (int q = 0; q < 2; ++q) {
        int ib = q * 32 + kg * 8;
        Bt[(ot * 2 + q) * 64 + lane] =
            uint4v{pk2bf(root2[(ib + 0) * HDIM + o], root2[(ib + 1) * HDIM + o]),
                   pk2bf(root2[(ib + 2) * HDIM + o], root2[(ib + 3) * HDIM + o]),
                   pk2bf(root2[(ib + 4) * HDIM + o], root2[(ib + 5) * HDIM + o]),
                   pk2bf(root2[(ib + 6) * HDIM + o], root2[(ib + 7) * HDIM + o])};
    }
}

// Per-channel sum & sumsq over N rows -> stats[0:64]=sum, stats[64:128]=sumsq (pre-zeroed)
__global__ void k_stats(const float* __restrict__ hbuf, float* stats) {
    int c = threadIdx.x & 63;
    int r = threadIdx.x >> 6;
    int rowsPer = blockDim.x >> 6;
    float s = 0.f, q = 0.f;
    for (int n = blockIdx.x * rowsPer + r; n < N_NODES; n += gridDim.x * rowsPer) {
        float v = hbuf[n * HDIM + c];
        s += v;
        q = fmaf(v, v, q);
    }
    __shared__ float ls[4][64], lq[4][64];
    ls[r][c] = s;
    lq[r][c] = q;
    __syncthreads();
    if (r == 0) {
        s = ls[0][c] + ls[1][c] + ls[2][c] + ls[3][c];
        q = lq[0][c] + lq[1][c] + lq[2][c] + lq[3][c];
        atomicAdd(&stats[c], s);
        atomicAdd(&stats[64 + c], q);
    }
}

__global__ void k_finalize(const float* stats_in, const float* __restrict__ g,
                           const float* __restrict__ beta, float* as_out) {
    int c = threadIdx.x;
    float mu = stats_in[c] * (1.f / N_NODES);
    float var = stats_in[64 + c] * (1.f / N_NODES) - mu * mu;
    var = fmaxf(var, 0.f);
    float a = g[c] * rsqrtf(var + BN_EPS);
    as_out[c] = a;
    as_out[64 + c] = beta[c] - mu * a;
}

// MFMA apply1: v = relu(BN1(h1)) (written to h1n f32), h2 = b2 + v @ root2 via MFMA.
// One wave per 16 nodes. A: lane holds node=(lane&15), channels kg*8..+8 (kg=lane>>4),
// chunk q adds +32. h2 aliases h1 safely: wave reads its rows fully before storing.
__global__ void k_apply1(const float* h1, const float* __restrict__ as1,
                         const uint4v* __restrict__ Bt, const float* __restrict__ b2,
                         float* __restrict__ h1n, float* h2) {
    int lane = threadIdx.x & 63;
    int m = lane & 15, kg = lane >> 4, orow4 = (lane >> 4) * 4;
    int tile = blockIdx.x * 4 + (threadIdx.x >> 6);
    int nb = tile * 16;
    if (nb >= N_NODES) return;
    int node = nb + m;
    const float* hr = h1 + (size_t)node * HDIM;

    // BN scale/shift for this lane's channels (broadcast float4 reads)
    float4 a0 = *(const float4*)(as1 + kg * 8), a1 = *(const float4*)(as1 + kg * 8 + 4);
    float4 s0 = *(const float4*)(as1 + 64 + kg * 8), s1 = *(const float4*)(as1 + 64 + kg * 8 + 4);
    float4 a2 = *(const float4*)(as1 + 32 + kg * 8), a3 = *(const float4*)(as1 + 32 + kg * 8 + 4);
    float4 s2 = *(const float4*)(as1 + 96 + kg * 8), s3 = *(const float4*)(as1 + 96 + kg * 8 + 4);

    float4 v0 = *(const float4*)(hr + kg * 8), v1 = *(const float4*)(hr + kg * 8 + 4);
    float4 v2 = *(const float4*)(hr + 32 + kg * 8), v3 = *(const float4*)(hr + 32 + kg * 8 + 4);

    float r0[8], r1[8];
#pragma unroll
    for (int p = 0; p < 4; ++p) {
        r0[p]     = fmaxf(fmaf((&v0.x)[p], (&a0.x)[p], (&s0.x)[p]), 0.f);
        r0[p + 4] = fmaxf(fmaf((&v1.x)[p], (&a1.x)[p], (&s1.x)[p]), 0.f);
        r1[p]     = fmaxf(fmaf((&v2.x)[p], (&a2.x)[p], (&s2.x)[p]), 0.f);
        r1[p + 4] = fmaxf(fmaf((&v3.x)[p], (&a3.x)[p], (&s3.x)[p]), 0.f);
    }
    // store h1n (f32, conv2 reads float4 rows)
    *(float4*)(h1n + (size_t)node * HDIM + kg * 8)     = float4{r0[0], r0[1], r0[2], r0[3]};
    *(float4*)(h1n + (size_t)node * HDIM + kg * 8 + 4) = float4{r0[4], r0[5], r0[6], r0[7]};
    *(float4*)(h1n + (size_t)node * HDIM + 32 + kg * 8)     = float4{r1[0], r1[1], r1[2], r1[3]};
    *(float4*)(h1n + (size_t)node * HDIM + 32 + kg * 8 + 4) = float4{r1[4], r1[5], r1[6], r1[7]};

    bfrag A0 = __builtin_bit_cast(bfrag, uint4v{pk2bf(r0[0], r0[1]), pk2bf(r0[2], r0[3]),
                                                pk2bf(r0[4], r0[5]), pk2bf(r0[6], r0[7])});
    bfrag A1 = __builtin_bit_cast(bfrag, uint4v{pk2bf(r1[0], r1[1]), pk2bf(r1[2], r1[3]),
                                                pk2bf(r1[4], r1[5]), pk2bf(r1[6], r1[7])});

    const facc zero4 = {0.f, 0.f, 0.f, 0.f};
#pragma unroll
    for (int ot = 0; ot < 4; ++ot) {
        bfrag B0 = __builtin_bit_cast(bfrag, Bt[(ot * 2 + 0) * 64 + lane]);
        bfrag B1 = __builtin_bit_cast(bfrag, Bt[(ot * 2 + 1) * 64 + lane]);
        facc d = __builtin_amdgcn_mfma_f32_16x16x32_bf16(A0, B0, zero4, 0, 0, 0);
        d = __builtin_amdgcn_mfma_f32_16x16x32_bf16(A1, B1, d, 0, 0, 0);
        float bv = b2[ot * 16 + m];
#pragma unroll
        for (int j = 0; j < 4; ++j)
            h2[(size_t)(nb + orow4 + j) * HDIM + ot * 16 + m] = d[j] + bv;
    }
}

// out[n] = sigmoid( sum_c relu(BN2(h2[n][c])) * Wfc[c] + bfc )
__global__ void k_final(const float* __restrict__ h2, const float* __restrict__ as2,
                        const float* __restrict__ Wfc, const float* __restrict__ bfc,
                        float* __restrict__ out) {
    int lane = threadIdx.x & 63;
    int n = blockIdx.x * (blockDim.x >> 6) + (threadIdx.x >> 6);
    if (n >= N_NODES) return;
    float a = as2[lane], s = as2[64 + lane];
    float v = fmaxf(fmaf(h2[n * HDIM + lane], a, s), 0.f) * Wfc[lane];
#pragma unroll
    for (int off = 32; off > 0; off >>= 1) v += __shfl_xor(v, off, 64);
    if (lane == 0) out[n] = 1.f / (1.f + expf(-(v + bfc[0])));
}

extern "C" void kernel_launch(void* const* d_in, const int* in_sizes, int n_in,
                              void* d_out, int out_size, void* d_ws, size_t ws_size,
                              hipStream_t stream) {
    const float* x     = (const float*)d_in[0];
    const float* ea    = (const float*)d_in[1];
    const float* We1   = (const float*)d_in[2];
    const float* be1   = (const float*)d_in[3];
    const float* root1 = (const float*)d_in[4];
    const float* b1    = (const float*)d_in[5];
    const float* g1    = (const float*)d_in[6];
    const float* beta1 = (const float*)d_in[7];
    const float* We2   = (const float*)d_in[8];
    const float* be2   = (const float*)d_in[9];
    const float* root2 = (const float*)d_in[10];
    const float* b2    = (const float*)d_in[11];
    const float* g2    = (const float*)d_in[12];
    const float* beta2 = (const float*)d_in[13];
    const float* Wfc   = (const float*)d_in[14];
    const float* bfc   = (const float*)d_in[15];
    const int*   eidx  = (const int*)d_in[16];
    float* out = (float*)d_out;

    char* ws = (char*)d_ws;
    const size_t nbuf = (size_t)N_NODES * HDIM * sizeof(float);
    float* h1    = (float*)ws;            // [N,64]
    float* h1n   = (float*)(ws + nbuf);   // [N,64]
    float* h2    = h1;                    // alias: h1 dead after k_apply1 reads it
    float* stats = (float*)(ws + 2 * nbuf);
    uint4v* Bt   = (uint4v*)(ws + 2 * nbuf + 4096);   // 8*64 uint4 = 8KB

    hipMemsetAsync(stats, 0, 512 * sizeof(float), stream);
    k_packB<<<1, 256, 0, stream>>>(root2, Bt);

    const int edgeBlocks = 2 * ((N_EDGES / 32 + 3) / 4);  // 1564: o-half pairs
    const int nodeBlocks = (N_NODES + 3) / 4;
    const int tileBlocks = (N_NODES / 16 + 3) / 4;        // 782: 16-node MFMA tiles

    k_node1<<<512, 256, 0, stream>>>(x, root1, b1, h1);
    k_edge<FNODE, 2><<<edgeBlocks, 256, 0, stream>>>(x, ea, We1, be1, eidx, h1);
    k_stats<<<256, 256, 0, stream>>>(h1, stats);
    k_finalize<<<1, 64, 0, stream>>>(stats, g1, beta1, stats + 128);
    k_apply1<<<tileBlocks, 256, 0, stream>>>(h1, stats + 128, Bt, b2, h1n, h2);
    k_edge<HDIM, 4><<<edgeBlocks, 256, 0, stream>>>(h1n, ea, We2, be2, eidx, h2);
    k_stats<<<256, 256, 0, stream>>>(h2, stats + 256);
    k_finalize<<<1, 64, 0, stream>>>(stats + 256, g2, beta2, stats + 384);
    k_final<<<nodeBlocks, 256, 0, stream>>>(h2, stats + 384, Wfc, bfc, out);
}

// Round 11
// 184.613 us; speedup vs baseline: 2.1510x; 1.0010x over previous
//
#include <hip/hip_runtime.h>
#include <math.h>

#define N_NODES 50000
#define N_EDGES 100000
#define FNODE 22
#define HDIM 64
#define BN_EPS 1e-5f

typedef __attribute__((ext_vector_type(8))) short bfrag;   // 8 bf16 = A/B operand
typedef __attribute__((ext_vector_type(4))) float facc;    // 4 f32  = C/D
typedef __attribute__((ext_vector_type(4))) unsigned int uint4v;

__device__ __forceinline__ unsigned f2bf(float x) {  // RNE f32->bf16
    unsigned u = __float_as_uint(x);
    return (u + 0x7FFFu + ((u >> 16) & 1u)) >> 16;
}
__device__ __forceinline__ unsigned pk2bf(float lo, float hi) {
    return f2bf(lo) | (f2bf(hi) << 16);
}

// Pack a [K][64] weight matrix into MFMA B-fragments (16x16x32, K zero-padded to 32*NQ).
// Bt[(ot*NQ+q)*64 + lane]: o = ot*16+(lane&15), k = q*32 + (lane>>4)*8 + 0..7.
template <int K>
__global__ void k_packB(const float* __restrict__ W, uint4v* __restrict__ Bt) {
    constexpr int NQ = (K + 31) / 32;
    int t = threadIdx.x;
    int ot = t >> 6, lane = t & 63;
    int o = ot * 16 + (lane & 15);
    int kg = lane >> 4;
#pragma unroll
    for (int q = 0; q < NQ; ++q) {
        unsigned w[4];
#pragma unroll
        for (int p = 0; p < 4; ++p) {
            int k0 = q * 32 + kg * 8 + 2 * p;
            float lo = (k0 < K) ? W[k0 * HDIM + o] : 0.f;
            float hi = (k0 + 1 < K) ? W[(k0 + 1) * HDIM + o] : 0.f;
            w[p] = pk2bf(lo, hi);
        }
        Bt[(ot * NQ + q) * 64 + lane] = uint4v{w[0], w[1], w[2], w[3]};
    }
}

// MFMA node1: h1 = b1 + x @ root1, one wave per 16 nodes, K=22 zero-padded to 32.
// A: lane holds node=(lane&15), channels kg*8..+8 (kg=lane>>4, ch>=22 zero).
__global__ void k_node1(const float* __restrict__ x, const uint4v* __restrict__ Bt1,
                        const float* __restrict__ b1, float* __restrict__ h1) {
    int lane = threadIdx.x & 63;
    int m = lane & 15, kg = lane >> 4, orow4 = kg * 4;
    int tile = blockIdx.x * 4 + (threadIdx.x >> 6);
    int nb = tile * 16;
    if (nb >= N_NODES) return;
    const float* xr = x + (size_t)(nb + m) * FNODE;
    float xv[8];
#pragma unroll
    for (int p = 0; p < 4; ++p) {
        int c = kg * 8 + 2 * p;
        float2 v = (c + 1 < FNODE) ? *(const float2*)(xr + c) : float2{0.f, 0.f};
        xv[2 * p] = v.x; xv[2 * p + 1] = v.y;
    }
    bfrag A = __builtin_bit_cast(bfrag, uint4v{pk2bf(xv[0], xv[1]), pk2bf(xv[2], xv[3]),
                                               pk2bf(xv[4], xv[5]), pk2bf(xv[6], xv[7])});
    const facc zero4 = {0.f, 0.f, 0.f, 0.f};
#pragma unroll
    for (int ot = 0; ot < 4; ++ot) {
        bfrag B = __builtin_bit_cast(bfrag, Bt1[ot * 64 + lane]);
        facc d = __builtin_amdgcn_mfma_f32_16x16x32_bf16(A, B, zero4, 0, 0, 0);
        float bv = b1[ot * 16 + m];
#pragma unroll
        for (int j = 0; j < 4; ++j)
            h1[(size_t)(nb + orow4 + j) * HDIM + ot * 16 + m] = d[j] + bv;
    }
}

// MFMA edge kernel v7: R10 structure (o-split pairs, pre-assembled B-fragments in LDS,
// line-disjoint contiguous atomics) + SOFTWARE-PIPELINED h gather: next chunk's 8
// broadcast loads issue before current chunk's compute -> full-iteration latency cover.
// dst indices loaded in the epilogue only (keeps loop-body VGPR peak ~115 <= 128).
template <int IN, int CHUNK>
__launch_bounds__(256, 4)
__global__ void k_edge(const float* __restrict__ h, const float* __restrict__ ea,
                       const float* __restrict__ We, const float* __restrict__ be,
                       const int* __restrict__ eidx, float* __restrict__ out) {
    constexpr int INH = IN * HDIM;
    __shared__ uint4v Wf[IN * 32];   // [i*32 + oloc] = B-fragment {w01,w23,be,0}

    int obeg = (blockIdx.x & 1) * 32;
    int tileblk = blockIdx.x >> 1;

    for (int idx = threadIdx.x; idx < IN * 32; idx += 256) {
        int i = idx >> 5, oloc = idx & 31;
        int c = i * HDIM + obeg + oloc;
        Wf[idx] = uint4v{pk2bf(We[c], We[INH + c]),
                         pk2bf(We[2 * INH + c], We[3 * INH + c]),
                         f2bf(be[c]), 0u};
    }
    __syncthreads();

    int lane = threadIdx.x & 63;
    int e16 = lane & 15;
    int orow4 = (lane >> 4) * 4;
    int tile = tileblk * 4 + (threadIdx.x >> 6);
    int ebase = tile * 32;
    if (ebase >= N_EDGES) return;

    // A operands: lanes<16 carry k=0..4 = {ea[e], 1.0}; other k-slots zero
    bool act = lane < 16;
    float4 ea0 = ((const float4*)ea)[ebase + e16];
    float4 ea1 = ((const float4*)ea)[ebase + 16 + e16];
    unsigned aone = act ? 0x3F80u : 0u;
    bfrag A0 = __builtin_bit_cast(bfrag, uint4v{act ? pk2bf(ea0.x, ea0.y) : 0u,
                                                act ? pk2bf(ea0.z, ea0.w) : 0u, aone, 0u});
    bfrag A1 = __builtin_bit_cast(bfrag, uint4v{act ? pk2bf(ea1.x, ea1.y) : 0u,
                                                act ? pk2bf(ea1.z, ea1.w) : 0u, aone, 0u});

    // src row byte-offsets for this lane's 8 (group, reg) rows
    const char* hb = (const char*)h;
    unsigned offA[4], offB[4];
#pragma unroll
    for (int j = 0; j < 4; ++j) {
        offA[j] = (unsigned)eidx[ebase + orow4 + j] * (IN * 4);
        offB[j] = (unsigned)eidx[ebase + 16 + orow4 + j] * (IN * 4);
    }

    const facc zero4 = {0.f, 0.f, 0.f, 0.f};
    facc m0[2] = {zero4, zero4}, m1[2] = {zero4, zero4};

    float cA[4][CHUNK], cB[4][CHUNK];
    // preload chunk 0
#pragma unroll
    for (int j = 0; j < 4; ++j) {
        if constexpr (CHUNK == 4) {
            float4 v = *(const float4*)(hb + offA[j]);
            cA[j][0] = v.x; cA[j][1] = v.y; cA[j][2] = v.z; cA[j][3] = v.w;
            float4 u = *(const float4*)(hb + offB[j]);
            cB[j][0] = u.x; cB[j][1] = u.y; cB[j][2] = u.z; cB[j][3] = u.w;
        } else {
            float2 v = *(const float2*)(hb + offA[j]);
            cA[j][0] = v.x; cA[j][1] = v.y;
            float2 u = *(const float2*)(hb + offB[j]);
            cB[j][0] = u.x; cB[j][1] = u.y;
        }
    }

#pragma unroll
    for (int i0 = 0; i0 < IN; i0 += CHUNK) {
        // prefetch next chunk (last iter re-reads current; values unused)
        const int ip = (i0 + CHUNK < IN) ? (i0 + CHUNK) : i0;
        float nA[4][CHUNK], nB[4][CHUNK];
#pragma unroll
        for (int j = 0; j < 4; ++j) {
            if constexpr (CHUNK == 4) {
                float4 v = *(const float4*)(hb + offA[j] + (size_t)ip * 4);
                nA[j][0] = v.x; nA[j][1] = v.y; nA[j][2] = v.z; nA[j][3] = v.w;
                float4 u = *(const float4*)(hb + offB[j] + (size_t)ip * 4);
                nB[j][0] = u.x; nB[j][1] = u.y; nB[j][2] = u.z; nB[j][3] = u.w;
            } else {
                float2 v = *(const float2*)(hb + offA[j] + (size_t)ip * 4);
                nA[j][0] = v.x; nA[j][1] = v.y;
                float2 u = *(const float2*)(hb + offB[j] + (size_t)ip * 4);
                nB[j][0] = u.x; nB[j][1] = u.y;
            }
        }
        // compute current chunk
#pragma unroll
        for (int t = 0; t < 2; ++t) {
#pragma unroll
            for (int di = 0; di < CHUNK; ++di) {
                bfrag B = __builtin_bit_cast(bfrag, Wf[(i0 + di) * 32 + t * 16 + e16]);
                facc t0 = __builtin_amdgcn_mfma_f32_16x16x32_bf16(A0, B, zero4, 0, 0, 0);
                facc t1 = __builtin_amdgcn_mfma_f32_16x16x32_bf16(A1, B, zero4, 0, 0, 0);
#pragma unroll
                for (int j = 0; j < 4; ++j) {
                    m0[t][j] = fmaf(cA[j][di], fmaxf(t0[j], 0.f), m0[t][j]);
                    m1[t][j] = fmaf(cB[j][di], fmaxf(t1[j], 0.f), m1[t][j]);
                }
            }
        }
        // rotate buffers (register renaming after full unroll)
#pragma unroll
        for (int j = 0; j < 4; ++j)
#pragma unroll
            for (int di = 0; di < CHUNK; ++di) { cA[j][di] = nA[j][di]; cB[j][di] = nB[j][di]; }
    }

    // epilogue: dst rows loaded here (off the loop's register peak);
    // each atomic instr = 4 edges x 16 contiguous dwords (line-disjoint o-halves)
    int dA[4], dB[4];
#pragma unroll
    for (int j = 0; j < 4; ++j) {
        dA[j] = eidx[N_EDGES + ebase + orow4 + j];
        dB[j] = eidx[N_EDGES + ebase + 16 + orow4 + j];
    }
#pragma unroll
    for (int t = 0; t < 2; ++t) {
#pragma unroll
        for (int j = 0; j < 4; ++j) {
            atomicAdd(&out[(size_t)dA[j] * HDIM + obeg + t * 16 + e16], m0[t][j]);
            atomicAdd(&out[(size_t)dB[j] * HDIM + obeg + t * 16 + e16], m1[t][j]);
        }
    }
}

// Per-channel sum & sumsq over N rows -> stats[0:64]=sum, stats[64:128]=sumsq (pre-zeroed)
__global__ void k_stats(const float* __restrict__ hbuf, float* stats) {
    int c = threadIdx.x & 63;
    int r = threadIdx.x >> 6;
    int rowsPer = blockDim.x >> 6;
    float s = 0.f, q = 0.f;
    for (int n = blockIdx.x * rowsPer + r; n < N_NODES; n += gridDim.x * rowsPer) {
        float v = hbuf[n * HDIM + c];
        s += v;
        q = fmaf(v, v, q);
    }
    __shared__ float ls[4][64], lq[4][64];
    ls[r][c] = s;
    lq[r][c] = q;
    __syncthreads();
    if (r == 0) {
        s = ls[0][c] + ls[1][c] + ls[2][c] + ls[3][c];
        q = lq[0][c] + lq[1][c] + lq[2][c] + lq[3][c];
        atomicAdd(&stats[c], s);
        atomicAdd(&stats[64 + c], q);
    }
}

__global__ void k_finalize(const float* stats_in, const float* __restrict__ g,
                           const float* __restrict__ beta, float* as_out) {
    int c = threadIdx.x;
    float mu = stats_in[c] * (1.f / N_NODES);
    float var = stats_in[64 + c] * (1.f / N_NODES) - mu * mu;
    var = fmaxf(var, 0.f);
    float a = g[c] * rsqrtf(var + BN_EPS);
    as_out[c] = a;
    as_out[64 + c] = beta[c] - mu * a;
}

// MFMA apply1: v = relu(BN1(h1)) (stored to h1n f32), h2 = b2 + v @ root2.
// One wave per 16 nodes; h2 aliases h1 safely (wave reads its rows before writing).
__global__ void k_apply1(const float* h1, const float* __restrict__ as1,
                         const uint4v* __restrict__ Bt, const float* __restrict__ b2,
                         float* __restrict__ h1n, float* h2) {
    int lane = threadIdx.x & 63;
    int m = lane & 15, kg = lane >> 4, orow4 = (lane >> 4) * 4;
    int tile = blockIdx.x * 4 + (threadIdx.x >> 6);
    int nb = tile * 16;
    if (nb >= N_NODES) return;
    int node = nb + m;
    const float* hr = h1 + (size_t)node * HDIM;

    float4 a0 = *(const float4*)(as1 + kg * 8), a1 = *(const float4*)(as1 + kg * 8 + 4);
    float4 s0 = *(const float4*)(as1 + 64 + kg * 8), s1 = *(const float4*)(as1 + 64 + kg * 8 + 4);
    float4 a2 = *(const float4*)(as1 + 32 + kg * 8), a3 = *(const float4*)(as1 + 32 + kg * 8 + 4);
    float4 s2 = *(const float4*)(as1 + 96 + kg * 8), s3 = *(const float4*)(as1 + 96 + kg * 8 + 4);

    float4 v0 = *(const float4*)(hr + kg * 8), v1 = *(const float4*)(hr + kg * 8 + 4);
    float4 v2 = *(const float4*)(hr + 32 + kg * 8), v3 = *(const float4*)(hr + 32 + kg * 8 + 4);

    float r0[8], r1[8];
#pragma unroll
    for (int p = 0; p < 4; ++p) {
        r0[p]     = fmaxf(fmaf((&v0.x)[p], (&a0.x)[p], (&s0.x)[p]), 0.f);
        r0[p + 4] = fmaxf(fmaf((&v1.x)[p], (&a1.x)[p], (&s1.x)[p]), 0.f);
        r1[p]     = fmaxf(fmaf((&v2.x)[p], (&a2.x)[p], (&s2.x)[p]), 0.f);
        r1[p + 4] = fmaxf(fmaf((&v3.x)[p], (&a3.x)[p], (&s3.x)[p]), 0.f);
    }
    *(float4*)(h1n + (size_t)node * HDIM + kg * 8)     = float4{r0[0], r0[1], r0[2], r0[3]};
    *(float4*)(h1n + (size_t)node * HDIM + kg * 8 + 4) = float4{r0[4], r0[5], r0[6], r0[7]};
    *(float4*)(h1n + (size_t)node * HDIM + 32 + kg * 8)     = float4{r1[0], r1[1], r1[2], r1[3]};
    *(float4*)(h1n + (size_t)node * HDIM + 32 + kg * 8 + 4) = float4{r1[4], r1[5], r1[6], r1[7]};

    bfrag A0 = __builtin_bit_cast(bfrag, uint4v{pk2bf(r0[0], r0[1]), pk2bf(r0[2], r0[3]),
                                                pk2bf(r0[4], r0[5]), pk2bf(r0[6], r0[7])});
    bfrag A1 = __builtin_bit_cast(bfrag, uint4v{pk2bf(r1[0], r1[1]), pk2bf(r1[2], r1[3]),
                                                pk2bf(r1[4], r1[5]), pk2bf(r1[6], r1[7])});

    const facc zero4 = {0.f, 0.f, 0.f, 0.f};
#pragma unroll
    for (int ot = 0; ot < 4; ++ot) {
        bfrag B0 = __builtin_bit_cast(bfrag, Bt[(ot * 2 + 0) * 64 + lane]);
        bfrag B1 = __builtin_bit_cast(bfrag, Bt[(ot * 2 + 1) * 64 + lane]);
        facc d = __builtin_amdgcn_mfma_f32_16x16x32_bf16(A0, B0, zero4, 0, 0, 0);
        d = __builtin_amdgcn_mfma_f32_16x16x32_bf16(A1, B1, d, 0, 0, 0);
        float bv = b2[ot * 16 + m];
#pragma unroll
        for (int j = 0; j < 4; ++j)
            h2[(size_t)(nb + orow4 + j) * HDIM + ot * 16 + m] = d[j] + bv;
    }
}

// out[n] = sigmoid( sum_c relu(BN2(h2[n][c])) * Wfc[c] + bfc )
__global__ void k_final(const float* __restrict__ h2, const float* __restrict__ as2,
                        const float* __restrict__ Wfc, const float* __restrict__ bfc,
                        float* __restrict__ out) {
    int lane = threadIdx.x & 63;
    int n = blockIdx.x * (blockDim.x >> 6) + (threadIdx.x >> 6);
    if (n >= N_NODES) return;
    float a = as2[lane], s = as2[64 + lane];
    float v = fmaxf(fmaf(h2[n * HDIM + lane], a, s), 0.f) * Wfc[lane];
#pragma unroll
    for (int off = 32; off > 0; off >>= 1) v += __shfl_xor(v, off, 64);
    if (lane == 0) out[n] = 1.f / (1.f + expf(-(v + bfc[0])));
}

extern "C" void kernel_launch(void* const* d_in, const int* in_sizes, int n_in,
                              void* d_out, int out_size, void* d_ws, size_t ws_size,
                              hipStream_t stream) {
    const float* x     = (const float*)d_in[0];
    const float* ea    = (const float*)d_in[1];
    const float* We1   = (const float*)d_in[2];
    const float* be1   = (const float*)d_in[3];
    const float* root1 = (const float*)d_in[4];
    const float* b1    = (const float*)d_in[5];
    const float* g1    = (const float*)d_in[6];
    const float* beta1 = (const float*)d_in[7];
    const float* We2   = (const float*)d_in[8];
    const float* be2   = (const float*)d_in[9];
    const float* root2 = (const float*)d_in[10];
    const float* b2    = (const float*)d_in[11];
    const float* g2    = (const float*)d_in[12];
    const float* beta2 = (const float*)d_in[13];
    const float* Wfc   = (const float*)d_in[14];
    const float* bfc   = (const float*)d_in[15];
    const int*   eidx  = (const int*)d_in[16];
    float* out = (float*)d_out;

    char* ws = (char*)d_ws;
    const size_t nbuf = (size_t)N_NODES * HDIM * sizeof(float);
    float* h1    = (float*)ws;            // [N,64]
    float* h1n   = (float*)(ws + nbuf);   // [N,64]
    float* h2    = h1;                    // alias: h1 dead after k_apply1 reads it
    float* stats = (float*)(ws + 2 * nbuf);
    uint4v* Bt2  = (uint4v*)(ws + 2 * nbuf + 4096);           // root2 frags: 8*64*16B = 8KB
    uint4v* Bt1  = (uint4v*)(ws + 2 * nbuf + 4096 + 8192);    // root1 frags: 4*64*16B = 4KB

    hipMemsetAsync(stats, 0, 512 * sizeof(float), stream);
    k_packB<HDIM><<<1, 256, 0, stream>>>(root2, Bt2);
    k_packB<FNODE><<<1, 256, 0, stream>>>(root1, Bt1);

    const int edgeBlocks = 2 * ((N_EDGES / 32 + 3) / 4);  // 1564: o-half pairs
    const int nodeBlocks = (N_NODES + 3) / 4;
    const int tileBlocks = (N_NODES / 16 + 3) / 4;        // 782: 16-node MFMA tiles

    k_node1<<<tileBlocks, 256, 0, stream>>>(x, Bt1, b1, h1);
    k_edge<FNODE, 2><<<edgeBlocks, 256, 0, stream>>>(x, ea, We1, be1, eidx, h1);
    k_stats<<<256, 256, 0, stream>>>(h1, stats);
    k_finalize<<<1, 64, 0, stream>>>(stats, g1, beta1, stats + 128);
    k_apply1<<<tileBlocks, 256, 0, stream>>>(h1, stats + 128, Bt2, b2, h1n, h2);
    k_edge<HDIM, 4><<<edgeBlocks, 256, 0, stream>>>(h1n, ea, We2, be2, eidx, h2);
    k_stats<<<256, 256, 0, stream>>>(h2, stats + 256);
    k_finalize<<<1, 64, 0, stream>>>(stats + 256, g2, beta2, stats + 384);
    k_final<<<nodeBlocks, 256, 0, stream>>>(h2, stats + 384, Wfc, bfc, out);
}